// Round 6
// baseline (228.542 us; speedup 1.0000x reference)
//
#include <hip/hip_runtime.h>
#include <hip/hip_fp16.h>
#include <math.h>

#define BATCH 8
#define NBUK_MAX 512
#define BSHIFT 10                 // 1024 vertices per bucket
#define CAPB 6656                 // records/bucket: mean 6144, +6.5 sigma, guarded
#define PACK_MASK 0x7FFFFull      // 19-bit fields (N <= 524288)
#define EXP_T 1024
#define EXP_Q 4                   // faces per thread
#define EXP_FACES (EXP_T * EXP_Q) // 4096 faces per block -> 245 expand blocks
#define SCAN_T 256
#define SCAN_E 8
#define SCAN_TILE (SCAN_T * SCAN_E)

union H2U { __half2 h; unsigned u; };

__device__ __forceinline__ long long pack3(int v, int a, int b) {
    return (long long)(((unsigned long long)(unsigned)v) |
                       ((unsigned long long)(unsigned)a << 19) |
                       ((unsigned long long)(unsigned)b << 38));
}

// ---------------- K1: FUSED direct-scatter expand + repack (R16, unchanged) ----
__global__ __launch_bounds__(EXP_T) void expand_repack_kernel(
        const int* __restrict__ faces,
        int* __restrict__ cursor,          // [NBUK_MAX*16] (64B-padded counters)
        long long* __restrict__ recbuf,    // [NB][CAPB]
        const float* __restrict__ vert,
        uint2* __restrict__ vh,
        int N, int F, int expBlocks) {
    __shared__ int hist[NBUK_MAX];
    __shared__ int gb[NBUK_MAX];
    int tid = threadIdx.x;

    if ((int)blockIdx.x < expBlocks) {
        if (tid < NBUK_MAX) hist[tid] = 0;
        __syncthreads();

        int fbase = blockIdx.x * EXP_FACES;
        int idx[EXP_Q][3];
        bool val[EXP_Q];
        #pragma unroll
        for (int q = 0; q < EXP_Q; ++q) {
            int f = fbase + q * EXP_T + tid;          // coalesced per q
            val[q] = f < F;
            if (val[q]) {
                idx[q][0] = faces[3 * f + 0];
                idx[q][1] = faces[3 * f + 1];
                idx[q][2] = faces[3 * f + 2];
            } else {
                idx[q][0] = 0; idx[q][1] = 0; idx[q][2] = 0;
            }
        }

        int rr[EXP_Q][3];
        #pragma unroll
        for (int q = 0; q < EXP_Q; ++q) {
            if (val[q]) {
                rr[q][0] = atomicAdd(&hist[idx[q][0] >> BSHIFT], 1);
                rr[q][1] = atomicAdd(&hist[idx[q][1] >> BSHIFT], 1);
                rr[q][2] = atomicAdd(&hist[idx[q][2] >> BSHIFT], 1);
            }
        }
        __syncthreads();

        if (tid < NBUK_MAX) {
            int h = hist[tid];
            gb[tid] = (h > 0) ? atomicAdd(&cursor[tid * 16], h) : 0;
        }
        __syncthreads();

        #pragma unroll
        for (int q = 0; q < EXP_Q; ++q) {
            if (val[q]) {
                int i = idx[q][0], j = idx[q][1], k = idx[q][2];
                int b0 = i >> BSHIFT, b1 = j >> BSHIFT, b2 = k >> BSHIFT;
                int p0 = gb[b0] + rr[q][0];
                int p1 = gb[b1] + rr[q][1];
                int p2 = gb[b2] + rr[q][2];
                if (p0 < CAPB) recbuf[(size_t)b0 * CAPB + p0] = pack3(i, j, k);
                if (p1 < CAPB) recbuf[(size_t)b1 * CAPB + p1] = pack3(j, i, k);
                if (p2 < CAPB) recbuf[(size_t)b2 * CAPB + p2] = pack3(k, i, j);
            }
        }
    } else {
        int u = (blockIdx.x - expBlocks) * EXP_T + threadIdx.x;
        if (u < N * BATCH) {
            int v = u >> 3;
            int b = u & 7;
            size_t src = ((size_t)b * N + v) * 3;
            H2U xy, zw;
            xy.h = __floats2half2_rn(vert[src], vert[src + 1]);
            zw.h = __floats2half2_rn(vert[src + 2], 0.0f);
            uint2 w; w.x = xy.u; w.y = zw.u;
            vh[u] = w;   // u == v*8 + b
        }
    }
}

__device__ __forceinline__ void unpack_acc4(uint4 r,
        float& ax0, float& ay0, float& az0,
        float& ax1, float& ay1, float& az1) {
    H2U a, b, c, d; a.u = r.x; b.u = r.y; c.u = r.z; d.u = r.w;
    float2 f0 = __half22float2(a.h);
    float2 f1 = __half22float2(b.h);
    float2 f2 = __half22float2(c.h);
    float2 f3 = __half22float2(d.h);
    ax0 += f0.x; ay0 += f0.y; az0 += f1.x;
    ax1 += f2.x; ay1 += f2.y; az1 += f3.x;
}

// ---------------- K2: per-bucket CSR build in LDS + FUSED gather ----------------
// R17: gather loop restructured to batch-PAIRS. Each lane loads uint4 (16 B,
// two batches) instead of uint2 (8 B, one batch): 4 lanes/vertex not 8 ->
// per-edge lane-transactions halve (48M -> 24M device-wide). Same lines, same
// bytes (FETCH_SIZE should stay ~356 MB); tests the L1-transaction-rate model.
__global__ __launch_bounds__(1024, 8) void bucket_gather_kernel(
        const int* __restrict__ cursor,
        const long long* __restrict__ recbuf,
        const uint2* __restrict__ vh,
        float* __restrict__ out, int N) {
    __shared__ int cntL[1024];          // hist -> exclusive offset -> running cursor (=end)
    __shared__ int offL[1024];          // exclusive offsets
    __shared__ int wsumG[16];
    __shared__ int2 colbuf[CAPB];       // 52 KB; total LDS ~60 KB -> 2 blocks/CU
    int tid = threadIdx.x;
    int bid = blockIdx.x;
    int v0 = bid << BSHIFT;

    int rc = cursor[bid * 16];
    int rcnt = rc < CAPB ? rc : CAPB;   // overflow guard matches K1's stored records

    cntL[tid] = 0;
    __syncthreads();
    const long long* recs = recbuf + (size_t)bid * CAPB;
    for (int x = tid; x < rcnt; x += 1024) {
        int v = (int)((unsigned long long)recs[x] & PACK_MASK);
        atomicAdd(&cntL[v & 1023], 2);
    }
    __syncthreads();

    // ---- shuffle-wave inclusive scan of cntL[0..1023] (16 full waves) ----
    int myc = cntL[tid];
    int lane = tid & 63;
    int wv = tid >> 6;                          // 0..15
    int incl = myc;
    #pragma unroll
    for (int d = 1; d < 64; d <<= 1) {
        int t = __shfl_up(incl, d, 64);
        if (lane >= d) incl += t;
    }
    if (lane == 63) wsumG[wv] = incl;
    __syncthreads();
    int pre = 0;
    #pragma unroll
    for (int w = 0; w < 16; ++w)
        pre += (w < wv) ? wsumG[w] : 0;         // broadcast reads, conflict-free
    incl += pre;
    int myoff = incl - myc;
    cntL[tid] = myoff;                          // own-slot write; no cross-read yet
    offL[tid] = myoff;
    __syncthreads();

    for (int x = tid; x < rcnt; x += 1024) {
        unsigned long long r = (unsigned long long)recs[x];
        int v = (int)(r & PACK_MASK);
        int a = (int)((r >> 19) & PACK_MASK);
        int b = (int)((r >> 38) & PACK_MASK);
        int p = atomicAdd(&cntL[v & 1023], 2);  // LDS scatter, not global
        colbuf[p >> 1] = make_int2(a, b);
    }
    __syncthreads();                            // cntL[lv] now == off+cnt (end)

    // ---- gather: thread handles (v = v0 + (tid>>2) + 256*it, batches 2bp,2bp+1) ----
    const uint4* vh4 = (const uint4*)vh;        // vh4[v*4 + bp] = batches 2bp,2bp+1
    int bp = tid & 3;
    for (int it = 0; it < (1 << BSHIFT) / 256; ++it) {
        int lv = (tid >> 2) + 256 * it;
        int v = v0 + lv;
        if (v >= N) continue;
        int start = offL[lv];                   // 4-lane LDS broadcast
        int end = cntL[lv];
        int c = end - start;
        int e = start >> 1, e1 = end >> 1;

        float ax0 = 0.f, ay0 = 0.f, az0 = 0.f;
        float ax1 = 0.f, ay1 = 0.f, az1 = 0.f;
        for (; e + 2 <= e1; e += 2) {           // 4 independent uint4 gathers in flight
            int2 s01 = colbuf[e];
            int2 s23 = colbuf[e + 1];
            uint4 r0 = vh4[((size_t)s01.x << 2) + bp];
            uint4 r1 = vh4[((size_t)s01.y << 2) + bp];
            uint4 r2 = vh4[((size_t)s23.x << 2) + bp];
            uint4 r3 = vh4[((size_t)s23.y << 2) + bp];
            unpack_acc4(r0, ax0, ay0, az0, ax1, ay1, az1);
            unpack_acc4(r1, ax0, ay0, az0, ax1, ay1, az1);
            unpack_acc4(r2, ax0, ay0, az0, ax1, ay1, az1);
            unpack_acc4(r3, ax0, ay0, az0, ax1, ay1, az1);
        }
        for (; e < e1; ++e) {
            int2 ss = colbuf[e];
            uint4 r0 = vh4[((size_t)ss.x << 2) + bp];
            uint4 r1 = vh4[((size_t)ss.y << 2) + bp];
            unpack_acc4(r0, ax0, ay0, az0, ax1, ay1, az1);
            unpack_acc4(r1, ax0, ay0, az0, ax1, ay1, az1);
        }

        float invd = 1.0f / fmaxf((float)c, 1.0f);
        float sx0 = 0.f, sy0 = 0.f, sz0 = 0.f;
        float sx1 = 0.f, sy1 = 0.f, sz1 = 0.f;
        uint4 sw = vh4[((size_t)v << 2) + bp];
        unpack_acc4(sw, sx0, sy0, sz0, sx1, sy1, sz1);
        float l00 = ax0 * invd - sx0;
        float l01 = ay0 * invd - sy0;
        float l02 = az0 * invd - sz0;
        float l10 = ax1 * invd - sx1;
        float l11 = ay1 * invd - sy1;
        float l12 = az1 * invd - sz1;
        out[(size_t)(2 * bp)     * N + v] = sqrtf(l00 * l00 + l01 * l01 + l02 * l02);
        out[(size_t)(2 * bp + 1) * N + v] = sqrtf(l10 * l10 + l11 * l11 + l12 * l12);
    }
}

// ---------------- fp32 fallback (tiny ws / oversized N) — R10-proven ----------------

__global__ void count_only_kernel(const int* __restrict__ faces, int* __restrict__ cnt,
                                  int* __restrict__ rank, int F) {
    int f = blockIdx.x * blockDim.x + threadIdx.x;
    if (f >= F) return;
    rank[3 * f + 0] = atomicAdd(&cnt[faces[3 * f + 0]], 2);
    rank[3 * f + 1] = atomicAdd(&cnt[faces[3 * f + 1]], 2);
    rank[3 * f + 2] = atomicAdd(&cnt[faces[3 * f + 2]], 2);
}

__global__ void scan_sums_kernel(const int* __restrict__ cnt, int* __restrict__ bsums, int N) {
    __shared__ int sh[SCAN_T];
    int base = blockIdx.x * SCAN_TILE + threadIdx.x * SCAN_E;
    int s = 0;
    #pragma unroll
    for (int e = 0; e < SCAN_E; ++e)
        if (base + e < N) s += cnt[base + e];
    sh[threadIdx.x] = s;
    __syncthreads();
    for (int d = SCAN_T / 2; d > 0; d >>= 1) {
        if (threadIdx.x < (unsigned)d) sh[threadIdx.x] += sh[threadIdx.x + d];
        __syncthreads();
    }
    if (threadIdx.x == 0) bsums[blockIdx.x] = sh[0];
}

__global__ void scan_apply_kernel(const int* __restrict__ cnt, int* __restrict__ off,
                                  const int* __restrict__ bsums, int N, int nb) {
    __shared__ int shb[SCAN_T];
    __shared__ int sh[SCAN_T];
    int bv = ((int)threadIdx.x < nb) ? bsums[threadIdx.x] : 0;
    shb[threadIdx.x] = bv;
    __syncthreads();
    for (int d = 1; d < SCAN_T; d <<= 1) {
        int t = (threadIdx.x >= (unsigned)d) ? shb[threadIdx.x - d] : 0;
        __syncthreads();
        shb[threadIdx.x] += t;
        __syncthreads();
    }
    int block_prefix = (blockIdx.x > 0) ? shb[blockIdx.x - 1] : 0;

    int base = blockIdx.x * SCAN_TILE + threadIdx.x * SCAN_E;
    int vals[SCAN_E];
    int s = 0;
    #pragma unroll
    for (int e = 0; e < SCAN_E; ++e) {
        int v = (base + e < N) ? cnt[base + e] : 0;
        vals[e] = v; s += v;
    }
    sh[threadIdx.x] = s;
    __syncthreads();
    for (int d = 1; d < SCAN_T; d <<= 1) {
        int t = (threadIdx.x >= (unsigned)d) ? sh[threadIdx.x - d] : 0;
        __syncthreads();
        sh[threadIdx.x] += t;
        __syncthreads();
    }
    int excl = block_prefix + ((threadIdx.x > 0) ? sh[threadIdx.x - 1] : 0);
    #pragma unroll
    for (int e = 0; e < SCAN_E; ++e) {
        if (base + e < N) off[base + e] = excl;
        excl += vals[e];
    }
}

__global__ void fill_kernel(const int* __restrict__ faces, const int* __restrict__ off,
                            const int* __restrict__ rank, int* __restrict__ col, int F) {
    int f = blockIdx.x * blockDim.x + threadIdx.x;
    if (f >= F) return;
    int i = faces[3 * f + 0];
    int j = faces[3 * f + 1];
    int k = faces[3 * f + 2];
    int2* c2 = (int2*)col;
    c2[(off[i] + rank[3 * f + 0]) >> 1] = make_int2(j, k);
    c2[(off[j] + rank[3 * f + 1]) >> 1] = make_int2(i, k);
    c2[(off[k] + rank[3 * f + 2]) >> 1] = make_int2(i, j);
}

__global__ void gather_scalar_kernel(const float* __restrict__ vert,
                                     const int* __restrict__ cnt,
                                     const int* __restrict__ off,
                                     const int* __restrict__ col,
                                     float* __restrict__ out, int N) {
    int v = blockIdx.x * blockDim.x + threadIdx.x;
    if (v >= N) return;
    int c = cnt[v];
    int start = off[v];
    int end = start + c;
    float ax[BATCH], ay[BATCH], az[BATCH];
    #pragma unroll
    for (int b = 0; b < BATCH; ++b) { ax[b] = 0.f; ay[b] = 0.f; az[b] = 0.f; }
    for (int e = start; e < end; ++e) {
        int s = col[e];
        #pragma unroll
        for (int b = 0; b < BATCH; ++b) {
            size_t base = ((size_t)b * N + s) * 3;
            ax[b] += vert[base + 0];
            ay[b] += vert[base + 1];
            az[b] += vert[base + 2];
        }
    }
    float invd = 1.0f / fmaxf((float)c, 1.0f);
    #pragma unroll
    for (int b = 0; b < BATCH; ++b) {
        size_t base = ((size_t)b * N + v) * 3;
        float l0 = ax[b] * invd - vert[base + 0];
        float l1 = ay[b] * invd - vert[base + 1];
        float l2 = az[b] * invd - vert[base + 2];
        out[(size_t)b * N + v] = sqrtf(l0 * l0 + l1 * l1 + l2 * l2);
    }
}

// ---------------- launch ----------------

static inline size_t align256(size_t x) { return (x + 255) & ~(size_t)255; }

extern "C" void kernel_launch(void* const* d_in, const int* in_sizes, int n_in,
                              void* d_out, int out_size, void* d_ws, size_t ws_size,
                              hipStream_t stream) {
    const float* vert  = (const float*)d_in[0];
    const int*   faces = (const int*)d_in[1];
    float*       out   = (float*)d_out;

    int N = out_size / BATCH;      // 500000
    int F = in_sizes[1] / 3;       // 1000000
    int E = 6 * F;
    int NB = (N + (1 << BSHIFT) - 1) >> BSHIFT;   // 489 buckets

    char* ws = (char*)d_ws;

    // Fast-path layout: cursor(32KB) | vh[N*B] uint2 | rec[NB*CAPB] i64
    size_t o_cursor = 0;
    size_t o_vh     = NBUK_MAX * 64;
    size_t o_rec    = o_vh + align256((size_t)N * BATCH * sizeof(uint2));
    size_t need     = o_rec + (size_t)NB * CAPB * 8;

    if (ws_size >= need && N <= 524288 && NB <= NBUK_MAX) {
        int*       cursor = (int*)(ws + o_cursor);
        uint2*     vh     = (uint2*)(ws + o_vh);
        long long* rec    = (long long*)(ws + o_rec);

        (void)hipMemsetAsync(cursor, 0, NBUK_MAX * 64, stream);

        int expB = (F + EXP_FACES - 1) / EXP_FACES;       // 245
        int repB = (N * BATCH + EXP_T - 1) / EXP_T;       // 3907
        expand_repack_kernel<<<expB + repB, EXP_T, 0, stream>>>(
            faces, cursor, rec, vert, vh, N, F, expB);

        bucket_gather_kernel<<<NB, 1024, 0, stream>>>(cursor, rec, vh, out, N);
        return;
    }

    // ---- compact fp32 fallback (R10-proven correctness path) ----
    int threads = 256;
    int nb = (N + SCAN_TILE - 1) / SCAN_TILE;
    size_t f_cnt   = 0;
    size_t f_off   = align256((size_t)N * 4);
    size_t f_bsums = f_off + align256((size_t)N * 4);
    size_t f_col   = f_bsums + 4096;
    size_t f_rank  = f_col + align256((size_t)E * 4);

    int* cnt   = (int*)(ws + f_cnt);
    int* off   = (int*)(ws + f_off);
    int* bsums = (int*)(ws + f_bsums);
    int* col   = (int*)(ws + f_col);
    int* rank  = (int*)(ws + f_rank);

    (void)hipMemsetAsync(cnt, 0, (size_t)N * 4, stream);

    int cntBlocks = (F + threads - 1) / threads;
    count_only_kernel<<<cntBlocks, threads, 0, stream>>>(faces, cnt, rank, F);
    scan_sums_kernel<<<nb, SCAN_T, 0, stream>>>(cnt, bsums, N);
    scan_apply_kernel<<<nb, SCAN_T, 0, stream>>>(cnt, off, bsums, N, nb);
    fill_kernel<<<cntBlocks, threads, 0, stream>>>(faces, off, rank, col, F);
    gather_scalar_kernel<<<(N + threads - 1) / threads, threads, 0, stream>>>(
        vert, cnt, off, col, out, N);
}